// Round 8
// baseline (354.448 us; speedup 1.0000x reference)
//
#include <hip/hip_runtime.h>

// NT-Xent: BATCH=4096, DIM=512, TEMP=0.5
// loss = mean_i [ log(sum_{j!=i} exp(2*cos(z_i,z_j))) - 2*cos(z_i, z_partner) ]
// R8: single fused kernel (plus one tiny memset node). No cooperative API
// (R7's hipLaunchCooperativeKernel failed to launch). Normalization is done
// lazily via a deadlock-free claim-or-wait protocol on 64 row-group flags:
// the first block needing a group CAS-claims it, normalizes those 128 rows
// fp32->fp8 into zq, zeroes the rowsum slice, release-stores flag=2; other
// blocks acquire-spin (their producer is already executing => no deadlock at
// any occupancy). GEMM body = R5's proven 48us fp8 MX structure. Last block
// (done counter) computes sum(log(rowsum)) - possum and writes out.

#define NROWS 8192
#define HALF_N 4096
#define KD 512            // elements per row (= 512 B/row in fp8)
#define TILE 128
#define BK 128            // fp8 bytes of K per tile iteration
#define NT (NROWS / TILE) // 64 block-tiles per side
#define NTILES (NT * (NT + 1) / 2)   // 2080 triangular tiles

typedef unsigned char u8;
typedef __attribute__((ext_vector_type(4))) int i32x4;
typedef __attribute__((ext_vector_type(8))) int i32x8;
typedef __attribute__((ext_vector_type(4))) float f32x4;

__device__ inline void load16_to_lds(const u8* g, u8* l) {
  __builtin_amdgcn_global_load_lds((const __attribute__((address_space(1))) void*)g,
                                   (__attribute__((address_space(3))) void*)l,
                                   16, 0, 0);
}

// normalize one 128-row group into zq (fp8 e4m3) + zero its rowsum slice
__device__ void norm_group(int g, const float* __restrict__ zi,
                           const float* __restrict__ zj, u8* __restrict__ zq,
                           float* __restrict__ rowsum, int* flag,
                           int t, int wave, int lane) {
  for (int r = wave; r < TILE; r += 4) {
    const int row = g * TILE + r;
    const float* src = (row < HALF_N) ? (zi + (size_t)row * KD)
                                      : (zj + (size_t)(row - HALF_N) * KD);
    const float4 v0 = ((const float4*)src)[lane * 2];
    const float4 v1 = ((const float4*)src)[lane * 2 + 1];
    float ss = v0.x * v0.x + v0.y * v0.y + v0.z * v0.z + v0.w * v0.w +
               v1.x * v1.x + v1.y * v1.y + v1.z * v1.z + v1.w * v1.w;
#pragma unroll
    for (int m = 1; m < 64; m <<= 1) ss += __shfl_xor(ss, m);
    const float inv = rsqrtf(ss);            // norms ~22.6, EPS irrelevant
    int lo = __builtin_amdgcn_cvt_pk_fp8_f32(v0.x * inv, v0.y * inv, 0, false);
    lo = __builtin_amdgcn_cvt_pk_fp8_f32(v0.z * inv, v0.w * inv, lo, true);
    int hi = __builtin_amdgcn_cvt_pk_fp8_f32(v1.x * inv, v1.y * inv, 0, false);
    hi = __builtin_amdgcn_cvt_pk_fp8_f32(v1.z * inv, v1.w * inv, hi, true);
    ((int2*)(zq + (size_t)row * KD))[lane] = make_int2(lo, hi);
  }
  if (t < TILE) rowsum[g * TILE + t] = 0.f;
  __syncthreads();   // all stores done before release
  if (t == 0)
    __hip_atomic_store(flag, 2, __ATOMIC_RELEASE, __HIP_MEMORY_SCOPE_AGENT);
}

__global__ __launch_bounds__(256) void nt_fused(const float* __restrict__ zi,
                                                const float* __restrict__ zj,
                                                u8* __restrict__ zq,
                                                float* __restrict__ rowsum,
                                                int* __restrict__ ctrl,
                                                float* __restrict__ out) {
  float* possum = (float*)ctrl;    // ctrl[0]
  int* done = ctrl + 1;            // ctrl[1]
  int* flags = ctrl + 2;           // ctrl[2..65] — all zeroed by memset node

  __shared__ __attribute__((aligned(16))) u8 lA[TILE * BK];
  __shared__ __attribute__((aligned(16))) u8 lB[TILE * BK];
  __shared__ float lrow[TILE];
  __shared__ float lcol[TILE];
  __shared__ int sclaim;
  __shared__ int slast;

  // decode linear bid -> (tm, tn) with tn >= tm
  const int bid = blockIdx.x;
  int tm = (int)((float)(2 * NT + 1) * 0.5f -
                 sqrtf((float)(2 * NT + 1) * (float)(2 * NT + 1) * 0.25f - 2.0f * (float)bid));
  if (tm < 0) tm = 0;
  if (tm > NT - 1) tm = NT - 1;
  while ((tm + 1) * NT - ((tm + 1) * tm) / 2 <= bid) ++tm;
  while (tm * NT - (tm * (tm - 1)) / 2 > bid) --tm;
  const int tn = tm + (bid - (tm * NT - (tm * (tm - 1)) / 2));
  const bool diag = (tm == tn);
  const bool isPos = (tn - tm == 32);   // block diagonal holds sim[i][i+N]

  const int t = threadIdx.x;
  const int wave = t >> 6, lane = t & 63;

  // ---- claim-or-wait normalization of row groups tm, tn ----
  if (t == 0) {
    int c = 0;
    if (atomicCAS(&flags[tm], 0, 1) == 0) c |= 1;
    if (!diag && atomicCAS(&flags[tn], 0, 1) == 0) c |= 2;
    sclaim = c;
  }
  __syncthreads();
  if (sclaim & 1) norm_group(tm, zi, zj, zq, rowsum, &flags[tm], t, wave, lane);
  if (sclaim & 2) norm_group(tn, zi, zj, zq, rowsum, &flags[tn], t, wave, lane);
  if (t == 0) {
    while (__hip_atomic_load(&flags[tm], __ATOMIC_ACQUIRE,
                             __HIP_MEMORY_SCOPE_AGENT) != 2)
      __builtin_amdgcn_s_sleep(8);
    if (!diag)
      while (__hip_atomic_load(&flags[tn], __ATOMIC_ACQUIRE,
                               __HIP_MEMORY_SCOPE_AGENT) != 2)
        __builtin_amdgcn_s_sleep(8);
  }
  __syncthreads();

  // ---- GEMM (R5 structure) ----
  const int wm = wave >> 1, wn = wave & 1;
  const int c16 = lane & 15, quad = lane >> 4;
  const int q2 = quad * 2;
  const int rowA = tm * TILE, rowB = tn * TILE;
  const u8* Bt = diag ? lA : lB;     // diagonal blocks: B tile == A tile

  f32x4 acc[4][4] = {};

  for (int k0 = 0; k0 < KD; k0 += BK) {
    __syncthreads();
    // stage 128x128 fp8 (= 1024 chunks of 16B) per tile
#pragma unroll
    for (int it = 0; it < 4; ++it) {
      const int chunk = it * 256 + t;       // destination chunk position
      const int r = chunk >> 3, cpos = chunk & 7;
      const int c = cpos ^ (r & 7);         // source column chunk (swizzle)
      u8* dstA = &lA[(it * 256 + wave * 64) * 16];  // wave-uniform
      load16_to_lds(&zq[(size_t)(rowA + r) * KD + k0 + c * 16], dstA);
      if (!diag) {
        u8* dstB = &lB[(it * 256 + wave * 64) * 16];
        load16_to_lds(&zq[(size_t)(rowB + r) * KD + k0 + c * 16], dstB);
      }
    }
    __syncthreads();

    i32x8 bg[4];
#pragma unroll
    for (int ni = 0; ni < 4; ++ni) {
      const int rB = wn * 64 + ni * 16 + c16;
      const i32x4 bl = *(const i32x4*)&Bt[(rB * 8 + (q2 ^ (rB & 7))) * 16];
      const i32x4 bh = *(const i32x4*)&Bt[(rB * 8 + ((q2 + 1) ^ (rB & 7))) * 16];
      bg[ni] = (i32x8){bl[0], bl[1], bl[2], bl[3], bh[0], bh[1], bh[2], bh[3]};
    }
#pragma unroll
    for (int mi = 0; mi < 4; ++mi) {
      const int rA = wm * 64 + mi * 16 + c16;
      const i32x4 al = *(const i32x4*)&lA[(rA * 8 + (q2 ^ (rA & 7))) * 16];
      const i32x4 ah = *(const i32x4*)&lA[(rA * 8 + ((q2 + 1) ^ (rA & 7))) * 16];
      const i32x8 af = (i32x8){al[0], al[1], al[2], al[3], ah[0], ah[1], ah[2], ah[3]};
#pragma unroll
      for (int ni = 0; ni < 4; ++ni)
        acc[mi][ni] = __builtin_amdgcn_mfma_scale_f32_16x16x128_f8f6f4(
            af, bg[ni], acc[mi][ni],
            0, 0,                    // cbsz=fp8(e4m3), blgp=fp8(e4m3)
            0, 0x7F7F7F7F,           // scale A: opsel 0, E8M0 1.0
            0, 0x7F7F7F7F);          // scale B: opsel 0, E8M0 1.0
    }
  }

  // in-tile diagonal ownership: row(quad*4+r)==col(c16) <=> quad==c16>>2, r==c16&3
  const bool ownDiag = (quad == (c16 >> 2));
  const int rdiag = c16 & 3;

  // ---- positive pairs (pre-exp): sum 4*dot over this block's diagonal ----
  if (isPos && wm == wn) {
    float p = 0.f;
    if (ownDiag) {
#pragma unroll
      for (int mi = 0; mi < 4; ++mi) p += acc[mi][mi][rdiag];
    }
#pragma unroll
    for (int m = 1; m < 64; m <<= 1) p += __shfl_xor(p, m);
    if (lane == 0) atomicAdd(possum, 4.0f * p);
  }

  // ---- e = exp(2*sim) in place ----
#pragma unroll
  for (int mi = 0; mi < 4; ++mi)
#pragma unroll
    for (int ni = 0; ni < 4; ++ni)
#pragma unroll
      for (int r = 0; r < 4; ++r)
        acc[mi][ni][r] = __expf(2.0f * acc[mi][ni][r]);

  // ---- diagonal removal (diag blocks): zero exp(sim_ii) ----
  if (diag && wm == wn && ownDiag) {
#pragma unroll
    for (int mi = 0; mi < 4; ++mi) acc[mi][mi][rdiag] = 0.f;
  }

  if (t < TILE) { lrow[t] = 0.f; lcol[t] = 0.f; }
  __syncthreads();

  // row sums: reduce over ni (in-register) and c16 (shfl over lane bits 0-3)
#pragma unroll
  for (int mi = 0; mi < 4; ++mi) {
#pragma unroll
    for (int r = 0; r < 4; ++r) {
      float e = acc[mi][0][r] + acc[mi][1][r] + acc[mi][2][r] + acc[mi][3][r];
      e += __shfl_xor(e, 1);
      e += __shfl_xor(e, 2);
      e += __shfl_xor(e, 4);
      e += __shfl_xor(e, 8);
      if (c16 == 0) atomicAdd(&lrow[wm * 64 + mi * 16 + quad * 4 + r], e);
    }
  }
  // col sums: reduce over mi,r (in-register) and quad (shfl over lane bits 4-5)
  if (!diag) {
#pragma unroll
    for (int ni = 0; ni < 4; ++ni) {
      float g = 0.f;
#pragma unroll
      for (int mi = 0; mi < 4; ++mi)
#pragma unroll
        for (int r = 0; r < 4; ++r) g += acc[mi][ni][r];
      g += __shfl_xor(g, 16);
      g += __shfl_xor(g, 32);
      if (quad == 0) atomicAdd(&lcol[wn * 64 + ni * 16 + c16], g);
    }
  }
  __syncthreads();
  if (t < TILE) {
    atomicAdd(&rowsum[rowA + t], lrow[t]);
    if (!diag) atomicAdd(&rowsum[rowB + t], lcol[t]);
  }

  // ---- completion: last block finalizes ----
  __syncthreads();   // all this block's rowsum atomics executed
  if (t == 0) {
    const int me = __hip_atomic_fetch_add(done, 1, __ATOMIC_ACQ_REL,
                                          __HIP_MEMORY_SCOPE_AGENT);
    slast = (me == NTILES - 1);
  }
  __syncthreads();
  if (slast) {
    float s = 0.f;
    for (int i = t; i < NROWS; i += 256)
      s += logf(__hip_atomic_load(&rowsum[i], __ATOMIC_RELAXED,
                                  __HIP_MEMORY_SCOPE_AGENT));
#pragma unroll
    for (int m = 1; m < 64; m <<= 1) s += __shfl_xor(s, m);
    if (lane == 0) lrow[wave] = s;
    __syncthreads();
    if (t == 0) {
      const float ps = __hip_atomic_load(possum, __ATOMIC_RELAXED,
                                         __HIP_MEMORY_SCOPE_AGENT);
      out[0] = (lrow[0] + lrow[1] + lrow[2] + lrow[3] - ps) * (1.0f / NROWS);
    }
  }
}

extern "C" void kernel_launch(void* const* d_in, const int* in_sizes, int n_in,
                              void* d_out, int out_size, void* d_ws, size_t ws_size,
                              hipStream_t stream) {
  const float* zi = (const float*)d_in[0];
  const float* zj = (const float*)d_in[1];
  float* out = (float*)d_out;

  // ws layout: zq (8192*512 fp8 = 4 MB) | rowsum (8192 f32) | ctrl (66 ints)
  u8* zq = (u8*)d_ws;
  float* rowsum = (float*)((char*)d_ws + (size_t)NROWS * KD);
  int* ctrl = (int*)(rowsum + NROWS);

  hipMemsetAsync(ctrl, 0, 66 * sizeof(int), stream);
  nt_fused<<<NTILES, 256, 0, stream>>>(zi, zj, zq, rowsum, ctrl, out);
}

// Round 9
// 141.809 us; speedup vs baseline: 2.4995x; 2.4995x over previous
//
#include <hip/hip_runtime.h>

// NT-Xent: BATCH=4096, DIM=512, TEMP=0.5
// loss = mean_i [ log(sum_{j!=i} exp(2*cos(z_i,z_j))) - 2*cos(z_i, z_partner) ]
// R9: two plain kernels (R8's spin/claim protocol regressed 3x — cross-XCD
// acquire spam + serialized normalize; reverted). Node-count still matters:
// R8 measured the 2-node launch gap at ~14us vs ~62us for 3 nodes. So:
//   node 1: nt_normalize (fp32 -> unit-norm fp8 e4m3; zeroes rowsum+ctrl)
//   node 2: nt_gemm = R5's 48us triangular fp8 MX-GEMM + done-counter tail:
//           the last block to finish computes sum(log(rowsum)) - possum -> out.

#define NROWS 8192
#define HALF_N 4096
#define KD 512            // elements per row (= 512 B/row in fp8)
#define TILE 128
#define BK 128            // fp8 bytes of K per tile iteration
#define NT (NROWS / TILE) // 64 block-tiles per side
#define NTILES (NT * (NT + 1) / 2)   // 2080 triangular tiles

typedef unsigned char u8;
typedef __attribute__((ext_vector_type(4))) int i32x4;
typedef __attribute__((ext_vector_type(8))) int i32x8;
typedef __attribute__((ext_vector_type(4))) float f32x4;

__device__ inline void load16_to_lds(const u8* g, u8* l) {
  __builtin_amdgcn_global_load_lds((const __attribute__((address_space(1))) void*)g,
                                   (__attribute__((address_space(3))) void*)l,
                                   16, 0, 0);
}

// ---------------- normalize: z (fp32) -> zq (fp8 e4m3, unit rows) ------------
// wave-per-row: 4 rows/block, 2048 blocks. Also zeroes rowsum and ctrl.
__global__ __launch_bounds__(256) void nt_normalize(const float* __restrict__ zi,
                                                    const float* __restrict__ zj,
                                                    u8* __restrict__ zq,
                                                    float* __restrict__ rowsum,
                                                    int* __restrict__ ctrl) {
  const int t = threadIdx.x;
  if (t < 4) rowsum[blockIdx.x * 4 + t] = 0.f;
  if (blockIdx.x == 0 && t >= 8 && t < 10) ctrl[t - 8] = 0;  // possum, done

  const int wave = t >> 6, lane = t & 63;
  const int row = blockIdx.x * 4 + wave;
  const float* src = (row < HALF_N) ? (zi + (size_t)row * KD)
                                    : (zj + (size_t)(row - HALF_N) * KD);
  const float4 v0 = ((const float4*)src)[lane * 2];
  const float4 v1 = ((const float4*)src)[lane * 2 + 1];
  float ss = v0.x * v0.x + v0.y * v0.y + v0.z * v0.z + v0.w * v0.w +
             v1.x * v1.x + v1.y * v1.y + v1.z * v1.z + v1.w * v1.w;
#pragma unroll
  for (int m = 1; m < 64; m <<= 1) ss += __shfl_xor(ss, m);
  const float inv = rsqrtf(ss);              // norms ~22.6, EPS irrelevant
  int lo = __builtin_amdgcn_cvt_pk_fp8_f32(v0.x * inv, v0.y * inv, 0, false);
  lo = __builtin_amdgcn_cvt_pk_fp8_f32(v0.z * inv, v0.w * inv, lo, true);
  int hi = __builtin_amdgcn_cvt_pk_fp8_f32(v1.x * inv, v1.y * inv, 0, false);
  hi = __builtin_amdgcn_cvt_pk_fp8_f32(v1.z * inv, v1.w * inv, hi, true);
  ((int2*)(zq + (size_t)row * KD))[lane] = make_int2(lo, hi);
}

// ---------------- GEMM + fused epilogue + last-block finalize ---------------
// 128x128 tile per block, 4 waves in 2x2, each wave 4x4 MFMA tiles of 16x16,
// one mfma_scale_f32_16x16x128 per tile-pair per K-iteration (BK=128).
// LDS holds 16B chunks at r*8 + (c ^ (r&7)) (XOR swizzle). Staged with
// global_load_lds. Scales fixed at 1.0 (0x7F per E8M0 byte).
__global__ __launch_bounds__(256) void nt_gemm(const u8* __restrict__ zq,
                                               float* __restrict__ rowsum,
                                               int* __restrict__ ctrl,
                                               float* __restrict__ out) {
  float* possum = (float*)ctrl;    // ctrl[0]
  int* done = ctrl + 1;            // ctrl[1]

  __shared__ __attribute__((aligned(16))) u8 lA[TILE * BK];
  __shared__ __attribute__((aligned(16))) u8 lB[TILE * BK];
  __shared__ float lrow[TILE];
  __shared__ float lcol[TILE];
  __shared__ int slast;

  // decode linear bid -> (tm, tn) with tn >= tm
  const int bid = blockIdx.x;
  int tm = (int)((float)(2 * NT + 1) * 0.5f -
                 sqrtf((float)(2 * NT + 1) * (float)(2 * NT + 1) * 0.25f - 2.0f * (float)bid));
  if (tm < 0) tm = 0;
  if (tm > NT - 1) tm = NT - 1;
  while ((tm + 1) * NT - ((tm + 1) * tm) / 2 <= bid) ++tm;
  while (tm * NT - (tm * (tm - 1)) / 2 > bid) --tm;
  const int tn = tm + (bid - (tm * NT - (tm * (tm - 1)) / 2));
  const bool diag = (tm == tn);
  const bool isPos = (tn - tm == 32);   // block diagonal holds sim[i][i+N]

  const int t = threadIdx.x;
  const int wave = t >> 6, lane = t & 63;
  const int wm = wave >> 1, wn = wave & 1;
  const int c16 = lane & 15, quad = lane >> 4;
  const int q2 = quad * 2;

  const int rowA = tm * TILE, rowB = tn * TILE;
  const u8* Bt = diag ? lA : lB;     // diagonal blocks: B tile == A tile

  f32x4 acc[4][4] = {};

  for (int k0 = 0; k0 < KD; k0 += BK) {
    __syncthreads();
    // stage 128x128 fp8 (= 1024 chunks of 16B) per tile
#pragma unroll
    for (int it = 0; it < 4; ++it) {
      const int chunk = it * 256 + t;       // destination chunk position
      const int r = chunk >> 3, cpos = chunk & 7;
      const int c = cpos ^ (r & 7);         // source column chunk (swizzle)
      u8* dstA = &lA[(it * 256 + wave * 64) * 16];  // wave-uniform
      load16_to_lds(&zq[(size_t)(rowA + r) * KD + k0 + c * 16], dstA);
      if (!diag) {
        u8* dstB = &lB[(it * 256 + wave * 64) * 16];
        load16_to_lds(&zq[(size_t)(rowB + r) * KD + k0 + c * 16], dstB);
      }
    }
    __syncthreads();

    i32x8 bg[4];
#pragma unroll
    for (int ni = 0; ni < 4; ++ni) {
      const int rB = wn * 64 + ni * 16 + c16;
      const i32x4 bl = *(const i32x4*)&Bt[(rB * 8 + (q2 ^ (rB & 7))) * 16];
      const i32x4 bh = *(const i32x4*)&Bt[(rB * 8 + ((q2 + 1) ^ (rB & 7))) * 16];
      bg[ni] = (i32x8){bl[0], bl[1], bl[2], bl[3], bh[0], bh[1], bh[2], bh[3]};
    }
#pragma unroll
    for (int mi = 0; mi < 4; ++mi) {
      const int rA = wm * 64 + mi * 16 + c16;
      const i32x4 al = *(const i32x4*)&lA[(rA * 8 + (q2 ^ (rA & 7))) * 16];
      const i32x4 ah = *(const i32x4*)&lA[(rA * 8 + ((q2 + 1) ^ (rA & 7))) * 16];
      const i32x8 af = (i32x8){al[0], al[1], al[2], al[3], ah[0], ah[1], ah[2], ah[3]};
#pragma unroll
      for (int ni = 0; ni < 4; ++ni)
        acc[mi][ni] = __builtin_amdgcn_mfma_scale_f32_16x16x128_f8f6f4(
            af, bg[ni], acc[mi][ni],
            0, 0,                    // cbsz=fp8(e4m3), blgp=fp8(e4m3)
            0, 0x7F7F7F7F,           // scale A: opsel 0, E8M0 1.0
            0, 0x7F7F7F7F);          // scale B: opsel 0, E8M0 1.0
    }
  }

  // in-tile diagonal ownership: row(quad*4+r)==col(c16) <=> quad==c16>>2, r==c16&3
  const bool ownDiag = (quad == (c16 >> 2));
  const int rdiag = c16 & 3;

  // ---- positive pairs (pre-exp): sum 4*dot over this block's diagonal ----
  if (isPos && wm == wn) {
    float p = 0.f;
    if (ownDiag) {
#pragma unroll
      for (int mi = 0; mi < 4; ++mi) p += acc[mi][mi][rdiag];
    }
#pragma unroll
    for (int m = 1; m < 64; m <<= 1) p += __shfl_xor(p, m);
    if (lane == 0) atomicAdd(possum, 4.0f * p);
  }

  // ---- e = exp(2*sim) in place ----
#pragma unroll
  for (int mi = 0; mi < 4; ++mi)
#pragma unroll
    for (int ni = 0; ni < 4; ++ni)
#pragma unroll
      for (int r = 0; r < 4; ++r)
        acc[mi][ni][r] = __expf(2.0f * acc[mi][ni][r]);

  // ---- diagonal removal (diag blocks): zero exp(sim_ii) ----
  if (diag && wm == wn && ownDiag) {
#pragma unroll
    for (int mi = 0; mi < 4; ++mi) acc[mi][mi][rdiag] = 0.f;
  }

  if (t < TILE) { lrow[t] = 0.f; lcol[t] = 0.f; }
  __syncthreads();

  // row sums: reduce over ni (in-register) and c16 (shfl over lane bits 0-3)
#pragma unroll
  for (int mi = 0; mi < 4; ++mi) {
#pragma unroll
    for (int r = 0; r < 4; ++r) {
      float e = acc[mi][0][r] + acc[mi][1][r] + acc[mi][2][r] + acc[mi][3][r];
      e += __shfl_xor(e, 1);
      e += __shfl_xor(e, 2);
      e += __shfl_xor(e, 4);
      e += __shfl_xor(e, 8);
      if (c16 == 0) atomicAdd(&lrow[wm * 64 + mi * 16 + quad * 4 + r], e);
    }
  }
  // col sums: reduce over mi,r (in-register) and quad (shfl over lane bits 4-5)
  if (!diag) {
#pragma unroll
    for (int ni = 0; ni < 4; ++ni) {
      float g = 0.f;
#pragma unroll
      for (int mi = 0; mi < 4; ++mi)
#pragma unroll
        for (int r = 0; r < 4; ++r) g += acc[mi][ni][r];
      g += __shfl_xor(g, 16);
      g += __shfl_xor(g, 32);
      if (quad == 0) atomicAdd(&lcol[wn * 64 + ni * 16 + c16], g);
    }
  }
  __syncthreads();
  if (t < TILE) {
    atomicAdd(&rowsum[rowA + t], lrow[t]);
    if (!diag) atomicAdd(&rowsum[rowB + t], lcol[t]);
  }

  // ---- completion: last block to finish computes the loss (R8-proven) ----
  __syncthreads();   // all this block's rowsum atomics issued
  if (t == 0) {
    const int me = __hip_atomic_fetch_add(done, 1, __ATOMIC_ACQ_REL,
                                          __HIP_MEMORY_SCOPE_AGENT);
    slast = (me == NTILES - 1);
  }
  __syncthreads();
  if (slast) {
    float s = 0.f;
    for (int i = t; i < NROWS; i += 256)
      s += logf(__hip_atomic_load(&rowsum[i], __ATOMIC_RELAXED,
                                  __HIP_MEMORY_SCOPE_AGENT));
#pragma unroll
    for (int m = 1; m < 64; m <<= 1) s += __shfl_xor(s, m);
    if (lane == 0) lrow[wave] = s;
    __syncthreads();
    if (t == 0) {
      const float ps = __hip_atomic_load(possum, __ATOMIC_RELAXED,
                                         __HIP_MEMORY_SCOPE_AGENT);
      out[0] = (lrow[0] + lrow[1] + lrow[2] + lrow[3] - ps) * (1.0f / NROWS);
    }
  }
}

extern "C" void kernel_launch(void* const* d_in, const int* in_sizes, int n_in,
                              void* d_out, int out_size, void* d_ws, size_t ws_size,
                              hipStream_t stream) {
  const float* zi = (const float*)d_in[0];
  const float* zj = (const float*)d_in[1];
  float* out = (float*)d_out;

  // ws layout: zq (8192*512 fp8 = 4 MB) | rowsum (8192 f32) | ctrl (2 ints)
  u8* zq = (u8*)d_ws;
  float* rowsum = (float*)((char*)d_ws + (size_t)NROWS * KD);
  int* ctrl = (int*)(rowsum + NROWS);

  nt_normalize<<<NROWS / 4, 256, 0, stream>>>(zi, zj, zq, rowsum, ctrl);
  nt_gemm<<<NTILES, 256, 0, stream>>>(zq, rowsum, ctrl, out);
}